// Round 4
// baseline (444.284 us; speedup 1.0000x reference)
//
#include <hip/hip_runtime.h>

#define N_   32
#define C_   512
#define HW_  3136
#define W_   56
#define H_   56
#define CM_  128
#define P_   512

typedef __attribute__((ext_vector_type(8))) short bf16x8;
typedef __attribute__((ext_vector_type(4))) float f32x4;

__device__ inline ushort f2bf(float x) {
    unsigned u = __float_as_uint(x);
    u += 0x7fff + ((u >> 16) & 1);
    return (ushort)(u >> 16);
}

// ---- prep: pack conv_w / fuse_w into A-fragment layouts; zero gacc ----
__global__ __launch_bounds__(256) void prep_w(const float* __restrict__ conv_w,
                                              const float* __restrict__ fuse_w,
                                              ushort* __restrict__ Acv,
                                              ushort* __restrict__ Afu,
                                              float* __restrict__ gacc) {
    int idx = blockIdx.x * 256 + threadIdx.x;   // < 131072
    if (idx < 4096) gacc[idx] = 0.f;
    if (idx < 65536) {
        int ci = idx & 7, cm = (idx >> 3) & 127, cb = idx >> 10;
        Acv[idx] = f2bf(conv_w[cm * C_ + cb * 8 + ci]);
    } else {
        int j = idx - 65536;
        int ci = j & 7, p = (j >> 3) & 511, kb = j >> 12;
        Afu[j] = f2bf(fuse_w[p * CM_ + kb * 8 + ci]);
    }
}

// ---- gemm_f (fused transpose + pooled), T14 issue-early/pack-late:
//   f_t[n][pix][cm] = relu(conv_w @ x + b), MFMA, K=512, x read directly (f32 NCHW)
//   gacc[n][cm] += sum_px pre-bias acc
__global__ __launch_bounds__(256) void gemm_f(const float* __restrict__ x,
                                              const ushort* __restrict__ Acv,
                                              const float* __restrict__ conv_b,
                                              ushort* __restrict__ f_t,
                                              float* __restrict__ gacc) {
    int pixbase = blockIdx.x * 64, n = blockIdx.z;
    int t = threadIdx.x, wv = t >> 6, lane = t & 63, col = lane & 15, quad = lane >> 4;
    __shared__ ushort bsh[2][64 * 40];
    f32x4 z = {0.f, 0.f, 0.f, 0.f};
    f32x4 acc[2][4];
    #pragma unroll
    for (int mt = 0; mt < 2; mt++)
        #pragma unroll
        for (int ns = 0; ns < 4; ns++) acc[mt][ns] = z;

    // coalesced staging: thread t owns pixel (t&63), channels wv*8 .. wv*8+7
    int spix = t & 63, chq = wv * 8;
    const float* xb = &x[(size_t)n * C_ * HW_ + pixbase + spix];

    float v[8];
#define LOADV(c0)                                                              \
    {                                                                          \
        const float* xs = xb + (size_t)(c0) * HW_;                             \
        _Pragma("unroll")                                                      \
        for (int i = 0; i < 8; i++) v[i] = xs[(size_t)(chq + i) * HW_];        \
    }
#define PACKW(buf)                                                             \
    {                                                                          \
        unsigned p0 = (unsigned)f2bf(v[0]) | ((unsigned)f2bf(v[1]) << 16);     \
        unsigned p1 = (unsigned)f2bf(v[2]) | ((unsigned)f2bf(v[3]) << 16);     \
        unsigned p2 = (unsigned)f2bf(v[4]) | ((unsigned)f2bf(v[5]) << 16);     \
        unsigned p3 = (unsigned)f2bf(v[6]) | ((unsigned)f2bf(v[7]) << 16);     \
        *(uint4*)&bsh[buf][spix * 40 + chq] = make_uint4(p0, p1, p2, p3);      \
    }

    LOADV(0);
    PACKW(0);
    __syncthreads();
    int cur = 0;
    for (int cb0 = 0; cb0 < 16; cb0++) {
        // issue next tile's loads BEFORE the MFMAs; consume (pack) AFTER -> HBM
        // latency hides under the 8 MFMAs + other waves' work.
        if (cb0 < 15) LOADV((cb0 + 1) * 32);
        bf16x8 a[2], b[4];
        #pragma unroll
        for (int mt = 0; mt < 2; mt++)
            a[mt] = *(const bf16x8*)&Acv[(((cb0 * 4 + quad) * CM_) + wv * 32 + mt * 16 + col) * 8];
        #pragma unroll
        for (int ns = 0; ns < 4; ns++)
            b[ns] = *(const bf16x8*)&bsh[cur][(ns * 16 + col) * 40 + quad * 8];
        #pragma unroll
        for (int mt = 0; mt < 2; mt++)
            #pragma unroll
            for (int ns = 0; ns < 4; ns++)
                acc[mt][ns] = __builtin_amdgcn_mfma_f32_16x16x32_bf16(a[mt], b[ns], acc[mt][ns], 0, 0, 0);
        // safe: all waves finished reading bsh[cur^1] at the previous barrier
        if (cb0 < 15) PACKW(cur ^ 1);
        __syncthreads();
        cur ^= 1;
    }
#undef LOADV
#undef PACKW

    // ---- gacc partial sums ----
    #pragma unroll
    for (int mt = 0; mt < 2; mt++) {
        float ps0 = acc[mt][0][0] + acc[mt][1][0] + acc[mt][2][0] + acc[mt][3][0];
        float ps1 = acc[mt][0][1] + acc[mt][1][1] + acc[mt][2][1] + acc[mt][3][1];
        float ps2 = acc[mt][0][2] + acc[mt][1][2] + acc[mt][2][2] + acc[mt][3][2];
        float ps3 = acc[mt][0][3] + acc[mt][1][3] + acc[mt][2][3] + acc[mt][3][3];
        #pragma unroll
        for (int off = 1; off < 16; off <<= 1) {
            ps0 += __shfl_xor(ps0, off);
            ps1 += __shfl_xor(ps1, off);
            ps2 += __shfl_xor(ps2, off);
            ps3 += __shfl_xor(ps3, off);
        }
        if (col == 0) {
            int ocr = wv * 32 + mt * 16 + quad * 4;
            atomicAdd(&gacc[n * CM_ + ocr],     ps0);
            atomicAdd(&gacc[n * CM_ + ocr + 1], ps1);
            atomicAdd(&gacc[n * CM_ + ocr + 2], ps2);
            atomicAdd(&gacc[n * CM_ + ocr + 3], ps3);
        }
    }

    // ---- bias + relu + store f_t ----
    #pragma unroll
    for (int mt = 0; mt < 2; mt++) {
        int ocr = wv * 32 + mt * 16 + quad * 4;
        float b0 = conv_b[ocr], b1 = conv_b[ocr + 1], b2 = conv_b[ocr + 2], b3 = conv_b[ocr + 3];
        #pragma unroll
        for (int ns = 0; ns < 4; ns++) {
            int pix = pixbase + ns * 16 + col;
            ushort4 o;
            o.x = f2bf(fmaxf(acc[mt][ns][0] + b0, 0.f));
            o.y = f2bf(fmaxf(acc[mt][ns][1] + b1, 0.f));
            o.z = f2bf(fmaxf(acc[mt][ns][2] + b2, 0.f));
            o.w = f2bf(fmaxf(acc[mt][ns][3] + b3, 0.f));
            *(ushort4*)&f_t[((size_t)(n * HW_ + pix)) * CM_ + ocr] = o;
        }
    }
}

// ---- Wk in bf16 A-fragment layout ----
__global__ __launch_bounds__(256) void wk_frag(const float* __restrict__ gacc,
                                               const float* __restrict__ conv_b,
                                               const float* __restrict__ ck_w,
                                               const float* __restrict__ ck_b,
                                               const float* __restrict__ ckk_w,
                                               const float* __restrict__ ckk_b,
                                               ushort* __restrict__ Wkf) {
    int idx = blockIdx.x * 256 + threadIdx.x;   // exactly 4718592 total
    int ci = idx & 7, oc = (idx >> 3) & 127, icb = (idx >> 10) & 15, rest = idx >> 14;
    int kk = rest % 9, n = rest / 9;
    int ic = icb * 8 + ci;
    float gv = fmaxf(gacc[n * CM_ + ic] * (1.0f / (float)HW_) + conv_b[ic], 0.f);
    float ker = ck_w[kk] * gv + ck_b[kk];
    Wkf[idx] = f2bf(fmaxf(ckk_w[oc] * ker + ckk_b[oc], 0.f));
}

// ---- gemm_dyn_fuse (XCD-swizzled, LDS union, T14 reg-staged prefetch):
//   phase 1: y = adap_b + sum_{kk,ic} Wk*f(shifted), MFMA K=9*128 -> bf16 in LDS
//   phase 2: out = fuse_w @ y + fuse_b, MFMA K=128, y read from LDS
__global__ __launch_bounds__(256) void gemm_dyn_fuse(const ushort* __restrict__ f_t,
                                                     const ushort* __restrict__ Wkf,
                                                     const float* __restrict__ adap_b,
                                                     const ushort* __restrict__ Afu,
                                                     const float* __restrict__ fuse_b,
                                                     float* __restrict__ out) {
    // XCD swizzle: pin each n's 49 blocks to one XCD. Bijective for 1568 blocks.
    int lid = blockIdx.x;
    int j = lid >> 3;
    int n = (lid & 7) + 8 * (j / 49);
    int pixbase = (j % 49) * 64;
    int t = threadIdx.x, wv = t >> 6, lane = t & 63, col = lane & 15, quad = lane >> 4;
    int h_lo = pixbase / W_;
    // union: fsh (232*40 = 9280) dead before ysh (4*64*40 = 10240) is written
    __shared__ ushort smem[10240];
    ushort* fsh = smem;
    ushort* ysh = smem;
    int ldspix[4];
    #pragma unroll
    for (int ns = 0; ns < 4; ns++) {
        int pix = pixbase + ns * 16 + col;
        int h = pix / W_, w = pix - h * W_;
        ldspix[ns] = (h - h_lo) * 58 + w;
    }

    // ---- precompute per-thread staging addresses/predicates (928 uint4 slots) ----
    const ushort* fsrc[4];
    int ldst[4];          // LDS ushort offset, or -1 (no write)
    bool sval[4];         // global load valid (else zero-fill)
    #pragma unroll
    for (int it = 0; it < 4; it++) {
        int idx = it * 256 + t;
        ldst[it] = -1; sval[it] = false; fsrc[it] = f_t;
        if (idx < 928) {
            int lp = idx >> 2, ch = idx & 3;
            int r = lp / 58, cw = lp - r * 58;
            int hp = h_lo + r;
            ldst[it] = lp * 40 + ch * 8;
            if (hp >= 1 && hp <= H_ && cw >= 1 && cw <= W_) {
                sval[it] = true;
                fsrc[it] = &f_t[((size_t)(n * HW_ + (hp - 1) * W_ + cw - 1)) * CM_ + ch * 8];
            }
        }
    }
    uint4 vst[4];
#define STAGE_LOAD(ic0)                                                        \
    _Pragma("unroll")                                                          \
    for (int it = 0; it < 4; it++) {                                           \
        vst[it] = make_uint4(0u, 0u, 0u, 0u);                                  \
        if (sval[it]) vst[it] = *(const uint4*)(fsrc[it] + (ic0));             \
    }
#define STAGE_WRITE()                                                          \
    _Pragma("unroll")                                                          \
    for (int it = 0; it < 4; it++)                                             \
        if (ldst[it] >= 0) *(uint4*)&fsh[ldst[it]] = vst[it];

    f32x4 acc[2][4];
    #pragma unroll
    for (int mt = 0; mt < 2; mt++) {
        int ocr = wv * 32 + mt * 16 + quad * 4;
        f32x4 ab = {adap_b[ocr], adap_b[ocr + 1], adap_b[ocr + 2], adap_b[ocr + 3]};
        #pragma unroll
        for (int ns = 0; ns < 4; ns++) acc[mt][ns] = ab;
    }

    STAGE_LOAD(0);
    STAGE_WRITE();
    __syncthreads();
    for (int s = 0; s < 4; s++) {
        int ic0 = s * 32;
        // issue next step's f_t loads BEFORE the 72 MFMAs; write to LDS after.
        if (s < 3) STAGE_LOAD(ic0 + 32);
        #pragma unroll
        for (int dh = 0; dh < 3; dh++) {
            #pragma unroll
            for (int dw = 0; dw < 3; dw++) {
                int kk = dh * 3 + dw;
                bf16x8 a[2], b[4];
                #pragma unroll
                for (int mt = 0; mt < 2; mt++)
                    a[mt] = *(const bf16x8*)&Wkf[((((size_t)(n * 9 + kk) * 16) + (ic0 >> 3) + quad) * CM_ + wv * 32 + mt * 16 + col) * 8];
                #pragma unroll
                for (int ns = 0; ns < 4; ns++)
                    b[ns] = *(const bf16x8*)&fsh[(ldspix[ns] + dh * 58 + dw) * 40 + quad * 8];
                #pragma unroll
                for (int mt = 0; mt < 2; mt++)
                    #pragma unroll
                    for (int ns = 0; ns < 4; ns++)
                        acc[mt][ns] = __builtin_amdgcn_mfma_f32_16x16x32_bf16(a[mt], b[ns], acc[mt][ns], 0, 0, 0);
            }
        }
        __syncthreads();          // all waves done reading fsh for this step
        if (s < 3) {
            STAGE_WRITE();        // vmcnt waits here, hidden under the MFMAs above
            __syncthreads();      // fsh ready for next step
        }
    }
#undef STAGE_LOAD
#undef STAGE_WRITE

    // ---- y -> LDS (bf16), panel layout identical to fuse staging ----
    #pragma unroll
    for (int mt = 0; mt < 2; mt++) {
        #pragma unroll
        for (int ns = 0; ns < 4; ns++) {
            int lpix = ns * 16 + col;
            ushort4 o;
            o.x = f2bf(acc[mt][ns][0]);
            o.y = f2bf(acc[mt][ns][1]);
            o.z = f2bf(acc[mt][ns][2]);
            o.w = f2bf(acc[mt][ns][3]);
            *(ushort4*)&ysh[wv * 2560 + lpix * 40 + mt * 16 + quad * 4] = o;
        }
    }
    __syncthreads();

    // ---- fuse phase: 4 P-chunks of 128, K=128 from ysh ----
    #pragma unroll 1
    for (int pb = 0; pb < 4; pb++) {
        f32x4 z = {0.f, 0.f, 0.f, 0.f};
        f32x4 facc[2][4];
        #pragma unroll
        for (int mt = 0; mt < 2; mt++)
            #pragma unroll
            for (int ns = 0; ns < 4; ns++) facc[mt][ns] = z;
        #pragma unroll
        for (int cb0 = 0; cb0 < 4; cb0++) {
            bf16x8 a[2], b[4];
            #pragma unroll
            for (int mt = 0; mt < 2; mt++)
                a[mt] = *(const bf16x8*)&Afu[(((cb0 * 4 + quad) * P_) + pb * 128 + wv * 32 + mt * 16 + col) * 8];
            #pragma unroll
            for (int ns = 0; ns < 4; ns++)
                b[ns] = *(const bf16x8*)&ysh[cb0 * 2560 + (ns * 16 + col) * 40 + quad * 8];
            #pragma unroll
            for (int mt = 0; mt < 2; mt++)
                #pragma unroll
                for (int ns = 0; ns < 4; ns++)
                    facc[mt][ns] = __builtin_amdgcn_mfma_f32_16x16x32_bf16(a[mt], b[ns], facc[mt][ns], 0, 0, 0);
        }
        #pragma unroll
        for (int mt = 0; mt < 2; mt++) {
            int pr = pb * 128 + wv * 32 + mt * 16 + quad * 4;
            #pragma unroll
            for (int ns = 0; ns < 4; ns++) {
                int pix = pixbase + ns * 16 + col;
                #pragma unroll
                for (int r = 0; r < 4; r++)
                    out[((size_t)(n * P_ + pr + r)) * HW_ + pix] = facc[mt][ns][r] + fuse_b[pr + r];
            }
        }
    }
}

extern "C" void kernel_launch(void* const* d_in, const int* in_sizes, int n_in,
                              void* d_out, int out_size, void* d_ws, size_t ws_size,
                              hipStream_t stream) {
    const float* x      = (const float*)d_in[0];
    const float* conv_w = (const float*)d_in[1];
    const float* conv_b = (const float*)d_in[2];
    const float* ck_w   = (const float*)d_in[3];
    const float* ck_b   = (const float*)d_in[4];
    const float* ckk_w  = (const float*)d_in[5];
    const float* ckk_b  = (const float*)d_in[6];
    const float* adap_b = (const float*)d_in[7];
    const float* fuse_w = (const float*)d_in[8];
    const float* fuse_b = (const float*)d_in[9];
    float* out = (float*)d_out;

    ushort* f_t = (ushort*)d_ws;                       // 12,845,056 ushorts
    ushort* Wkf = f_t + (size_t)12845056;              // 4,718,592
    ushort* Acv = Wkf + (size_t)4718592;               // 65,536
    ushort* Afu = Acv + (size_t)65536;                 // 65,536
    float* gacc = (float*)(Afu + (size_t)65536);       // 4,096 floats

    prep_w<<<512, 256, 0, stream>>>(conv_w, fuse_w, Acv, Afu, gacc);
    gemm_f<<<dim3(49, 1, N_), 256, 0, stream>>>(x, Acv, conv_b, f_t, gacc);
    wk_frag<<<18432, 256, 0, stream>>>(gacc, conv_b, ck_w, ck_b, ckk_w, ckk_b, Wkf);
    gemm_dyn_fuse<<<dim3(1568), 256, 0, stream>>>(f_t, Wkf, adap_b, Afu, fuse_b, out);
}

// Round 5
// 434.562 us; speedup vs baseline: 1.0224x; 1.0224x over previous
//
#include <hip/hip_runtime.h>

#define N_   32
#define C_   512
#define HW_  3136
#define W_   56
#define H_   56
#define CM_  128
#define P_   512

typedef __attribute__((ext_vector_type(8))) short bf16x8;
typedef __attribute__((ext_vector_type(4))) float f32x4;

__device__ inline ushort f2bf(float x) {
    unsigned u = __float_as_uint(x);
    u += 0x7fff + ((u >> 16) & 1);
    return (ushort)(u >> 16);
}

// packed f32x2 -> bf16x2 (RNE), single instruction
__device__ inline unsigned pk2bf(float lo, float hi) {
    unsigned r;
    asm("v_cvt_pk_bf16_f32 %0, %1, %2" : "=v"(r) : "v"(lo), "v"(hi));
    return r;
}

// ---- prep: pack conv_w / fuse_w into A-fragment layouts; zero gacc ----
__global__ __launch_bounds__(256) void prep_w(const float* __restrict__ conv_w,
                                              const float* __restrict__ fuse_w,
                                              ushort* __restrict__ Acv,
                                              ushort* __restrict__ Afu,
                                              float* __restrict__ gacc) {
    int idx = blockIdx.x * 256 + threadIdx.x;   // < 131072
    if (idx < 4096) gacc[idx] = 0.f;
    if (idx < 65536) {
        int ci = idx & 7, cm = (idx >> 3) & 127, cb = idx >> 10;
        Acv[idx] = f2bf(conv_w[cm * C_ + cb * 8 + ci]);
    } else {
        int j = idx - 65536;
        int ci = j & 7, p = (j >> 3) & 511, kb = j >> 12;
        Afu[j] = f2bf(fuse_w[p * CM_ + kb * 8 + ci]);
    }
}

// ---- gemm_f (fused transpose + pooled):
//   f_t[n][pix][cm] = relu(conv_w @ x + b), MFMA, K=512, x read directly (f32 NCHW)
//   gacc[n][cm] += sum_px pre-bias acc
//   staging: thread owns 4 consecutive pixels x 1 channel pair ->
//            2 coalesced float4 loads + 4 cvt_pk + 4 ds_write_b32 per K-step
__global__ __launch_bounds__(256) void gemm_f(const float* __restrict__ x,
                                              const ushort* __restrict__ Acv,
                                              const float* __restrict__ conv_b,
                                              ushort* __restrict__ f_t,
                                              float* __restrict__ gacc) {
    int pixbase = blockIdx.x * 64, n = blockIdx.z;
    int t = threadIdx.x, wv = t >> 6, lane = t & 63, col = lane & 15, quad = lane >> 4;
    __shared__ ushort bsh[2][64 * 40];
    f32x4 z = {0.f, 0.f, 0.f, 0.f};
    f32x4 acc[2][4];
    #pragma unroll
    for (int mt = 0; mt < 2; mt++)
        #pragma unroll
        for (int ns = 0; ns < 4; ns++) acc[mt][ns] = z;

    int pg = (t & 15) * 4;    // 4 consecutive pixels
    int cp = (t >> 4) * 2;    // channel pair within the 32-channel K-step
    const float* xb = &x[((size_t)n * C_ + cp) * HW_ + pixbase + pg];

#define STAGE(cb0, buf)                                                        \
    {                                                                          \
        const float* xs = xb + (size_t)(cb0) * 32 * HW_;                       \
        float4 v0 = *(const float4*)xs;                                        \
        float4 v1 = *(const float4*)(xs + HW_);                                \
        *(unsigned*)&bsh[buf][(pg    ) * 40 + cp] = pk2bf(v0.x, v1.x);         \
        *(unsigned*)&bsh[buf][(pg + 1) * 40 + cp] = pk2bf(v0.y, v1.y);         \
        *(unsigned*)&bsh[buf][(pg + 2) * 40 + cp] = pk2bf(v0.z, v1.z);         \
        *(unsigned*)&bsh[buf][(pg + 3) * 40 + cp] = pk2bf(v0.w, v1.w);         \
    }

    STAGE(0, 0);
    __syncthreads();
    int cur = 0;
    for (int cb0 = 0; cb0 < 16; cb0++) {
        if (cb0 < 15) STAGE(cb0 + 1, cur ^ 1);
        bf16x8 a[2], b[4];
        #pragma unroll
        for (int mt = 0; mt < 2; mt++)
            a[mt] = *(const bf16x8*)&Acv[(((cb0 * 4 + quad) * CM_) + wv * 32 + mt * 16 + col) * 8];
        #pragma unroll
        for (int ns = 0; ns < 4; ns++)
            b[ns] = *(const bf16x8*)&bsh[cur][(ns * 16 + col) * 40 + quad * 8];
        #pragma unroll
        for (int mt = 0; mt < 2; mt++)
            #pragma unroll
            for (int ns = 0; ns < 4; ns++)
                acc[mt][ns] = __builtin_amdgcn_mfma_f32_16x16x32_bf16(a[mt], b[ns], acc[mt][ns], 0, 0, 0);
        __syncthreads();
        cur ^= 1;
    }
#undef STAGE

    // ---- gacc partial sums ----
    #pragma unroll
    for (int mt = 0; mt < 2; mt++) {
        float ps0 = acc[mt][0][0] + acc[mt][1][0] + acc[mt][2][0] + acc[mt][3][0];
        float ps1 = acc[mt][0][1] + acc[mt][1][1] + acc[mt][2][1] + acc[mt][3][1];
        float ps2 = acc[mt][0][2] + acc[mt][1][2] + acc[mt][2][2] + acc[mt][3][2];
        float ps3 = acc[mt][0][3] + acc[mt][1][3] + acc[mt][2][3] + acc[mt][3][3];
        #pragma unroll
        for (int off = 1; off < 16; off <<= 1) {
            ps0 += __shfl_xor(ps0, off);
            ps1 += __shfl_xor(ps1, off);
            ps2 += __shfl_xor(ps2, off);
            ps3 += __shfl_xor(ps3, off);
        }
        if (col == 0) {
            int ocr = wv * 32 + mt * 16 + quad * 4;
            atomicAdd(&gacc[n * CM_ + ocr],     ps0);
            atomicAdd(&gacc[n * CM_ + ocr + 1], ps1);
            atomicAdd(&gacc[n * CM_ + ocr + 2], ps2);
            atomicAdd(&gacc[n * CM_ + ocr + 3], ps3);
        }
    }

    // ---- bias + relu + store f_t ----
    #pragma unroll
    for (int mt = 0; mt < 2; mt++) {
        int ocr = wv * 32 + mt * 16 + quad * 4;
        float b0 = conv_b[ocr], b1 = conv_b[ocr + 1], b2 = conv_b[ocr + 2], b3 = conv_b[ocr + 3];
        #pragma unroll
        for (int ns = 0; ns < 4; ns++) {
            int pix = pixbase + ns * 16 + col;
            uint2 o;
            o.x = pk2bf(fmaxf(acc[mt][ns][0] + b0, 0.f), fmaxf(acc[mt][ns][1] + b1, 0.f));
            o.y = pk2bf(fmaxf(acc[mt][ns][2] + b2, 0.f), fmaxf(acc[mt][ns][3] + b3, 0.f));
            *(uint2*)&f_t[((size_t)(n * HW_ + pix)) * CM_ + ocr] = o;
        }
    }
}

// ---- Wk in bf16 A-fragment layout ----
__global__ __launch_bounds__(256) void wk_frag(const float* __restrict__ gacc,
                                               const float* __restrict__ conv_b,
                                               const float* __restrict__ ck_w,
                                               const float* __restrict__ ck_b,
                                               const float* __restrict__ ckk_w,
                                               const float* __restrict__ ckk_b,
                                               ushort* __restrict__ Wkf) {
    int idx = blockIdx.x * 256 + threadIdx.x;   // exactly 4718592 total
    int ci = idx & 7, oc = (idx >> 3) & 127, icb = (idx >> 10) & 15, rest = idx >> 14;
    int kk = rest % 9, n = rest / 9;
    int ic = icb * 8 + ci;
    float gv = fmaxf(gacc[n * CM_ + ic] * (1.0f / (float)HW_) + conv_b[ic], 0.f);
    float ker = ck_w[kk] * gv + ck_b[kk];
    Wkf[idx] = f2bf(fmaxf(ckk_w[oc] * ker + ckk_b[oc], 0.f));
}

// ---- gemm_dyn_fuse (XCD-swizzled, LDS union) — R3 structure:
//   phase 1: y = adap_b + sum_{kk,ic} Wk*f(shifted), MFMA K=9*128 -> bf16 in LDS
//   phase 2: out = fuse_w @ y + fuse_b, MFMA K=128, y read from LDS
__global__ __launch_bounds__(256) void gemm_dyn_fuse(const ushort* __restrict__ f_t,
                                                     const ushort* __restrict__ Wkf,
                                                     const float* __restrict__ adap_b,
                                                     const ushort* __restrict__ Afu,
                                                     const float* __restrict__ fuse_b,
                                                     float* __restrict__ out) {
    // XCD swizzle: pin each n's 49 blocks to one XCD. Bijective for 1568 blocks.
    int lid = blockIdx.x;
    int j = lid >> 3;
    int n = (lid & 7) + 8 * (j / 49);
    int pixbase = (j % 49) * 64;
    int t = threadIdx.x, wv = t >> 6, lane = t & 63, col = lane & 15, quad = lane >> 4;
    int h_lo = pixbase / W_;
    // union: fsh (232*40 = 9280) dead before ysh (4*64*40 = 10240) is written
    __shared__ ushort smem[10240];
    ushort* fsh = smem;
    ushort* ysh = smem;
    int ldspix[4];
    #pragma unroll
    for (int ns = 0; ns < 4; ns++) {
        int pix = pixbase + ns * 16 + col;
        int h = pix / W_, w = pix - h * W_;
        ldspix[ns] = (h - h_lo) * 58 + w;
    }
    f32x4 acc[2][4];
    #pragma unroll
    for (int mt = 0; mt < 2; mt++) {
        int ocr = wv * 32 + mt * 16 + quad * 4;
        f32x4 ab = {adap_b[ocr], adap_b[ocr + 1], adap_b[ocr + 2], adap_b[ocr + 3]};
        #pragma unroll
        for (int ns = 0; ns < 4; ns++) acc[mt][ns] = ab;
    }
    for (int ic0 = 0; ic0 < CM_; ic0 += 32) {
        #pragma unroll
        for (int it = 0; it < 4; it++) {
            int idx = it * 256 + t;
            if (idx < 928) {
                int lp = idx >> 2, ch = idx & 3;
                int r = lp / 58, cw = lp - r * 58;
                int hp = h_lo + r;
                uint4 v = {0u, 0u, 0u, 0u};
                if (hp >= 1 && hp <= H_ && cw >= 1 && cw <= W_)
                    v = *(const uint4*)&f_t[((size_t)(n * HW_ + (hp - 1) * W_ + cw - 1)) * CM_ + ic0 + ch * 8];
                *(uint4*)&fsh[lp * 40 + ch * 8] = v;
            }
        }
        __syncthreads();
        #pragma unroll
        for (int dh = 0; dh < 3; dh++) {
            #pragma unroll
            for (int dw = 0; dw < 3; dw++) {
                int kk = dh * 3 + dw;
                bf16x8 a[2], b[4];
                #pragma unroll
                for (int mt = 0; mt < 2; mt++)
                    a[mt] = *(const bf16x8*)&Wkf[((((size_t)(n * 9 + kk) * 16) + (ic0 >> 3) + quad) * CM_ + wv * 32 + mt * 16 + col) * 8];
                #pragma unroll
                for (int ns = 0; ns < 4; ns++)
                    b[ns] = *(const bf16x8*)&fsh[(ldspix[ns] + dh * 58 + dw) * 40 + quad * 8];
                #pragma unroll
                for (int mt = 0; mt < 2; mt++)
                    #pragma unroll
                    for (int ns = 0; ns < 4; ns++)
                        acc[mt][ns] = __builtin_amdgcn_mfma_f32_16x16x32_bf16(a[mt], b[ns], acc[mt][ns], 0, 0, 0);
            }
        }
        __syncthreads();
    }

    // ---- y -> LDS (bf16), panel layout identical to fuse staging ----
    #pragma unroll
    for (int mt = 0; mt < 2; mt++) {
        #pragma unroll
        for (int ns = 0; ns < 4; ns++) {
            int lpix = ns * 16 + col;
            uint2 o;
            o.x = pk2bf(acc[mt][ns][0], acc[mt][ns][1]);
            o.y = pk2bf(acc[mt][ns][2], acc[mt][ns][3]);
            *(uint2*)&ysh[wv * 2560 + lpix * 40 + mt * 16 + quad * 4] = o;
        }
    }
    __syncthreads();

    // ---- fuse phase: 4 P-chunks of 128, K=128 from ysh ----
    #pragma unroll 1
    for (int pb = 0; pb < 4; pb++) {
        f32x4 z = {0.f, 0.f, 0.f, 0.f};
        f32x4 facc[2][4];
        #pragma unroll
        for (int mt = 0; mt < 2; mt++)
            #pragma unroll
            for (int ns = 0; ns < 4; ns++) facc[mt][ns] = z;
        #pragma unroll
        for (int cb0 = 0; cb0 < 4; cb0++) {
            bf16x8 a[2], b[4];
            #pragma unroll
            for (int mt = 0; mt < 2; mt++)
                a[mt] = *(const bf16x8*)&Afu[(((cb0 * 4 + quad) * P_) + pb * 128 + wv * 32 + mt * 16 + col) * 8];
            #pragma unroll
            for (int ns = 0; ns < 4; ns++)
                b[ns] = *(const bf16x8*)&ysh[cb0 * 2560 + (ns * 16 + col) * 40 + quad * 8];
            #pragma unroll
            for (int mt = 0; mt < 2; mt++)
                #pragma unroll
                for (int ns = 0; ns < 4; ns++)
                    facc[mt][ns] = __builtin_amdgcn_mfma_f32_16x16x32_bf16(a[mt], b[ns], facc[mt][ns], 0, 0, 0);
        }
        #pragma unroll
        for (int mt = 0; mt < 2; mt++) {
            int pr = pb * 128 + wv * 32 + mt * 16 + quad * 4;
            #pragma unroll
            for (int ns = 0; ns < 4; ns++) {
                int pix = pixbase + ns * 16 + col;
                #pragma unroll
                for (int r = 0; r < 4; r++)
                    out[((size_t)(n * P_ + pr + r)) * HW_ + pix] = facc[mt][ns][r] + fuse_b[pr + r];
            }
        }
    }
}

extern "C" void kernel_launch(void* const* d_in, const int* in_sizes, int n_in,
                              void* d_out, int out_size, void* d_ws, size_t ws_size,
                              hipStream_t stream) {
    const float* x      = (const float*)d_in[0];
    const float* conv_w = (const float*)d_in[1];
    const float* conv_b = (const float*)d_in[2];
    const float* ck_w   = (const float*)d_in[3];
    const float* ck_b   = (const float*)d_in[4];
    const float* ckk_w  = (const float*)d_in[5];
    const float* ckk_b  = (const float*)d_in[6];
    const float* adap_b = (const float*)d_in[7];
    const float* fuse_w = (const float*)d_in[8];
    const float* fuse_b = (const float*)d_in[9];
    float* out = (float*)d_out;

    ushort* f_t = (ushort*)d_ws;                       // 12,845,056 ushorts
    ushort* Wkf = f_t + (size_t)12845056;              // 4,718,592
    ushort* Acv = Wkf + (size_t)4718592;               // 65,536
    ushort* Afu = Acv + (size_t)65536;                 // 65,536
    float* gacc = (float*)(Afu + (size_t)65536);       // 4,096 floats

    prep_w<<<512, 256, 0, stream>>>(conv_w, fuse_w, Acv, Afu, gacc);
    gemm_f<<<dim3(49, 1, N_), 256, 0, stream>>>(x, Acv, conv_b, f_t, gacc);
    wk_frag<<<18432, 256, 0, stream>>>(gacc, conv_b, ck_w, ck_b, ckk_w, ckk_b, Wkf);
    gemm_dyn_fuse<<<dim3(1568), 256, 0, stream>>>(f_t, Wkf, adap_b, Afu, fuse_b, out);
}